// Round 6
// baseline (253.813 us; speedup 1.0000x reference)
//
#include <hip/hip_runtime.h>
#include <cstdint>
#include <cstddef>

typedef __attribute__((ext_vector_type(8))) short short8;   // 8 bf16 = 4 VGPRs (MFMA A/B frag)
typedef __attribute__((ext_vector_type(4))) float floatx4;  // MFMA C/D frag

__device__ __forceinline__ float bf2f(unsigned short u) {
  union { unsigned int i; float f; } c; c.i = ((unsigned int)u) << 16; return c.f;
}
__device__ __forceinline__ unsigned short f2bf(float f) {
  union { float f; unsigned int i; } c; c.f = f;
  unsigned int r = c.i + 0x7fffu + ((c.i >> 16) & 1u);  // round-nearest-even
  return (unsigned short)(r >> 16);
}
__device__ __forceinline__ unsigned int fbits(float f) {
  union { float f; unsigned int i; } c; c.f = f; return c.i;
}

// async global->LDS, 16 B per lane; LDS dest = wave-uniform base + lane*16 (m97/m104)
__device__ __forceinline__ void glds16(const unsigned short* g, unsigned short* l) {
  __builtin_amdgcn_global_load_lds((const __attribute__((address_space(1))) void*)g,
                                   (__attribute__((address_space(3))) void*)l, 16, 0, 0);
}

// ---- 32x32 transpose+cvt tile helper (256 threads, 4 rows/thread) ----
__device__ __forceinline__ void tr_tile(const float* __restrict__ in,
                                        unsigned short* __restrict__ out,
                                        int R, int C, int bx, int by, int tid,
                                        unsigned short (*t)[33]) {
  const int cx = tid & 31, rl = tid >> 5;
#pragma unroll
  for (int i = 0; i < 4; ++i)
    t[rl + i * 8][cx] = f2bf(in[(size_t)(by * 32 + rl + i * 8) * C + bx * 32 + cx]);
  __syncthreads();
  const int oc = by * 32 + cx;
#pragma unroll
  for (int i = 0; i < 4; ++i)
    out[(size_t)(bx * 32 + rl + i * 8) * R + oc] = t[cx][rl + i * 8];
}

// ---- fused prep: W_qkv^T (3072 blks) + W_out^T (1024 blks) + x cvt (4096 blks) ----
__global__ __launch_bounds__(256) void k_prep(const float* __restrict__ x,
                                              const float* __restrict__ Wq,
                                              const float* __restrict__ Wo,
                                              unsigned short* __restrict__ x_bf,
                                              unsigned short* __restrict__ WTq,
                                              unsigned short* __restrict__ WTo) {
  __shared__ unsigned short t[32][33];
  const int bid = blockIdx.x, tid = threadIdx.x;
  if (bid < 3072) {
    tr_tile(Wq, WTq, 1024, 3072, bid % 96, bid / 96, tid, t);
  } else if (bid < 4096) {
    int v = bid - 3072;
    tr_tile(Wo, WTo, 1024, 1024, v & 31, v >> 5, tid, t);
  } else {
    int i = (bid - 4096) * 256 + tid;
    float4 v = ((const float4*)x)[i];
    ushort4 o = { f2bf(v.x), f2bf(v.y), f2bf(v.z), f2bf(v.w) };
    ((ushort4*)x_bf)[i] = o;
  }
}

// ---------------- GEMM: C[M][N] = A[M][K] * BT[N][K]^T, bf16 in ----------------
// m97 structure, MT x 128 tile, BK=32, global_load_lds width-16 staging.
template <int MT, bool F32OUT>
__global__ __launch_bounds__(256) void k_gemm_bt(const unsigned short* __restrict__ A,
                                                 const unsigned short* __restrict__ BT,
                                                 void* __restrict__ Cout,
                                                 int M, int N, int K) {
  constexpr int NI = MT / 32;  // per-wave m-frag count (4 or 2)
  __shared__ unsigned short As[MT * 32];
  __shared__ unsigned short Bs[128 * 32];
  const int bm = blockIdx.x * MT, bn = blockIdx.y * 128;
  const int tid = threadIdx.x;
  const int wave = tid >> 6, lane = tid & 63;
  const int wm = (wave & 1) * (MT / 2), wn = (wave >> 1) * 64;
  const int lrow = lane & 15, lgrp = lane >> 4;
  floatx4 acc[NI][4] = {};

  const int lr4 = lane >> 2, lc8 = (lane & 3) * 8;
  const int br0 = wave * 32;
  const unsigned short* Bg0 = BT + (size_t)(bn + br0 + lr4) * K + lc8;
  const unsigned short* Bg1 = BT + (size_t)(bn + br0 + 16 + lr4) * K + lc8;
  unsigned short* lB0 = &Bs[br0 * 32];
  unsigned short* lB1 = &Bs[(br0 + 16) * 32];
  const int ar0 = wave * (MT / 4);
  const unsigned short* Ag0 = A + (size_t)(bm + ar0 + lr4) * K + lc8;
  const unsigned short* Ag1 = A + (size_t)(bm + ar0 + 16 + lr4) * K + lc8;  // MT==128 only
  unsigned short* lA0 = &As[ar0 * 32];
  unsigned short* lA1 = &As[(ar0 + 16) * 32];

  for (int k0 = 0; k0 < K; k0 += 32) {
    glds16(Ag0 + k0, lA0);
    if (MT == 128) glds16(Ag1 + k0, lA1);
    glds16(Bg0 + k0, lB0);
    glds16(Bg1 + k0, lB1);
    __syncthreads();
    short8 a[NI], bfr[4];
#pragma unroll
    for (int i = 0; i < NI; ++i)
      a[i] = *(const short8*)&As[(wm + i * 16 + lrow) * 32 + lgrp * 8];
#pragma unroll
    for (int j = 0; j < 4; ++j)
      bfr[j] = *(const short8*)&Bs[(wn + j * 16 + lrow) * 32 + lgrp * 8];
#pragma unroll
    for (int i = 0; i < NI; ++i)
#pragma unroll
      for (int j = 0; j < 4; ++j)
        acc[i][j] = __builtin_amdgcn_mfma_f32_16x16x32_bf16(a[i], bfr[j], acc[i][j], 0, 0, 0);
    __syncthreads();
  }
#pragma unroll
  for (int i = 0; i < NI; ++i)
#pragma unroll
    for (int j = 0; j < 4; ++j)
#pragma unroll
      for (int r = 0; r < 4; ++r) {
        int m = bm + wm + i * 16 + lgrp * 4 + r;
        int n = bn + wn + j * 16 + lrow;
        if (F32OUT)
          ((float*)Cout)[(size_t)m * N + n] = acc[i][j][r];
        else
          ((unsigned short*)Cout)[(size_t)m * N + n] = f2bf(acc[i][j][r]);
      }
}

// ---- fused LN (4096 blks) + V transpose (4096 blks); both read qkv ----
// LN: q out folded by 0.125*log2(e) so flash uses exp2 directly.
__global__ __launch_bounds__(256) void k_lnv(const unsigned short* __restrict__ qkv,
                                             const float* __restrict__ q_scale,
                                             const float* __restrict__ k_scale,
                                             unsigned short* __restrict__ q_n,
                                             unsigned short* __restrict__ k_n,
                                             unsigned short* __restrict__ VT) {
  const int bid = blockIdx.x, tid = threadIdx.x;
  if (bid < 4096) {
    const int tok = bid;
    const int wave = tid >> 6, lane = tid & 63;
    __shared__ float red[2][4];
    const unsigned short* row = qkv + (size_t)tok * 3072;
#pragma unroll
    for (int seg = 0; seg < 2; ++seg) {
      const unsigned short* p  = row + seg * 1024;
      const float* sc = seg ? k_scale : q_scale;
      unsigned short* outp = (seg ? k_n : q_n) + (size_t)tok * 1024;
      ushort4 u = *(const ushort4*)&p[tid * 4];
      float xv[4] = { bf2f(u.x), bf2f(u.y), bf2f(u.z), bf2f(u.w) };
      float sum = xv[0] + xv[1] + xv[2] + xv[3];
      float sq  = xv[0]*xv[0] + xv[1]*xv[1] + xv[2]*xv[2] + xv[3]*xv[3];
      for (int off = 32; off; off >>= 1) {
        sum += __shfl_down(sum, off, 64);
        sq  += __shfl_down(sq,  off, 64);
      }
      if (lane == 0) { red[0][wave] = sum; red[1][wave] = sq; }
      __syncthreads();
      sum = red[0][0] + red[0][1] + red[0][2] + red[0][3];
      sq  = red[1][0] + red[1][1] + red[1][2] + red[1][3];
      __syncthreads();
      float mean = sum * (1.0f / 1024.0f);
      float var  = sq * (1.0f / 1024.0f) - mean * mean;
      float rstd = rsqrtf(var + 1e-6f);
      if (seg == 0) rstd *= 0.18033688011112042f;  // 0.125 * log2(e)
      float4 su = *(const float4*)&sc[tid * 4];
      ushort4 o;
      o.x = f2bf((xv[0] - mean) * rstd * su.x);
      o.y = f2bf((xv[1] - mean) * rstd * su.y);
      o.z = f2bf((xv[2] - mean) * rstd * su.z);
      o.w = f2bf((xv[3] - mean) * rstd * su.w);
      *(ushort4*)&outp[tid * 4] = o;
    }
  } else {
    // V transpose tile: v-part [b,s,h*64+hd] -> VT[(b*16+h)*64+hd][s]
    __shared__ unsigned short t[32][33];
    const int v = bid - 4096;
    const int bh = v & 31, b = bh >> 4, h = bh & 15;
    const int sy = (v >> 5) & 63, hx = v >> 11;   // s-tile 0..63, hd-tile 0..1
    const int cx = tid & 31, rl = tid >> 5;
#pragma unroll
    for (int i = 0; i < 4; ++i)
      t[rl + i * 8][cx] =
        qkv[(size_t)(b * 2048 + sy * 32 + rl + i * 8) * 3072 + 2048 + h * 64 + hx * 32 + cx];
    __syncthreads();
#pragma unroll
    for (int i = 0; i < 4; ++i)
      VT[((size_t)bh * 64 + hx * 32 + rl + i * 8) * 2048 + sy * 32 + cx] = t[cx][rl + i * 8];
  }
}

// ------------------------------ flash attention ------------------------------
// Fixed-max softmax (m=0, validated r4/r5). S^T = K Q^T (lane: t=lgrp*4+r,
// q=lrow). P stored TRUNCATED via high-half packing (2 VALU per pair vs ~5/val
// RNE); l accumulated exact in fp32 -> relative bias <=2^-10, negligible.
template <int TB, bool MASKED>
__device__ __forceinline__ void attn_tile(int t0, int qcol,
    const short8 qa0, const short8 qa1,
    const unsigned short* Ks, const unsigned short* Vs, unsigned short* Psw,
    floatx4 (&o)[4], float& lsum, int lrow, int lgrp) {
#pragma unroll
  for (int tb = 0; tb < TB; ++tb) {
    floatx4 st = {};
    short8 kb0 = *(const short8*)&Ks[(tb * 16 + lrow) * 72 + lgrp * 8];
    st = __builtin_amdgcn_mfma_f32_16x16x32_bf16(kb0, qa0, st, 0, 0, 0);
    short8 kb1 = *(const short8*)&Ks[(tb * 16 + lrow) * 72 + 32 + lgrp * 8];
    st = __builtin_amdgcn_mfma_f32_16x16x32_bf16(kb1, qa1, st, 0, 0, 0);
    float p0 = exp2f(st[0]), p1 = exp2f(st[1]);
    float p2 = exp2f(st[2]), p3 = exp2f(st[3]);
    if (MASKED) {
      const int tbase = t0 + tb * 16 + lgrp * 4;
      p0 = (tbase     <= qcol) ? p0 : 0.0f;
      p1 = (tbase + 1 <= qcol) ? p1 : 0.0f;
      p2 = (tbase + 2 <= qcol) ? p2 : 0.0f;
      p3 = (tbase + 3 <= qcol) ? p3 : 0.0f;
    }
    lsum += (p0 + p1) + (p2 + p3);
    uint2 pu;
    pu.x = (fbits(p0) >> 16) | (fbits(p1) & 0xFFFF0000u);  // trunc-pack
    pu.y = (fbits(p2) >> 16) | (fbits(p3) & 0xFFFF0000u);
    *(uint2*)&Psw[lrow * 132 + tb * 16 + lgrp * 4] = pu;
  }
#pragma unroll
  for (int kk = 0; kk < TB / 2; ++kk) {
    short8 pa = *(const short8*)&Psw[lrow * 132 + kk * 32 + lgrp * 8];
#pragma unroll
    for (int nb = 0; nb < 4; ++nb) {
      short8 vb = *(const short8*)&Vs[(nb * 16 + lrow) * 132 + kk * 32 + lgrp * 8];
      o[nb] = __builtin_amdgcn_mfma_f32_16x16x32_bf16(pa, vb, o[nb], 0, 0, 0);
    }
  }
}

// grid (32 bh, 32 qt): linear id % 8 = bh % 8 -> one bh per XCD (L2 locality).
// qt reversed: heavy diagonal blocks first. block 256 = 4 waves x 16 Q-rows.
// LDS 52224 B (strides 72/132/132) -> 3 blocks/CU within 160 KiB.
__global__ __launch_bounds__(256) void k_flash(const unsigned short* __restrict__ q_n,
                                               const unsigned short* __restrict__ k_n,
                                               const unsigned short* __restrict__ VT,
                                               unsigned short* __restrict__ ctx) {
  const int S = 2048, D = 1024;
  const int bh = blockIdx.x, b = bh >> 4, h = bh & 15;
  const int qt = 31 - (int)blockIdx.y;
  const int q0 = qt * 64;
  const int tid = threadIdx.x, wave = tid >> 6, lane = tid & 63;
  const int lrow = lane & 15, lgrp = lane >> 4;
  __shared__ unsigned short Ks[128 * 72];     // [t][hd]
  __shared__ unsigned short Vs[64 * 132];     // [hd][t]
  __shared__ unsigned short Ps[4][16 * 132];  // per-wave P [q][t]
  unsigned short* Psw = Ps[wave];

  const unsigned short* kg = k_n + (size_t)(b * S) * D + h * 64;
  const unsigned short* vg = VT + (size_t)bh * 64 * S;
  const int ksr = tid >> 3, ksc = (tid & 7) * 8;    // K staging: 32 rows/pass
  const int vsr = tid >> 4, vsc = (tid & 15) * 8;   // V staging: 16 rows/pass

  const int q0w = q0 + wave * 16;
  const int qcol = q0w + lrow;                       // this lane's q row (S^T col)
  const unsigned short* qp = q_n + (size_t)(b * S + qcol) * D + h * 64;
  const short8 qa0 = *(const short8*)(qp + lgrp * 8);
  const short8 qa1 = *(const short8*)(qp + 32 + lgrp * 8);
  floatx4 o[4] = {};
  float lsum = 0.0f;

  const int tend = q0 + 64;
  for (int t0 = 0; t0 < tend; t0 += 128) {
#pragma unroll
    for (int j = 0; j < 4; ++j) {
      int r = ksr + j * 32;
      *(int4*)&Ks[r * 72 + ksc] = *(const int4*)(kg + (size_t)(t0 + r) * D + ksc);
    }
#pragma unroll
    for (int j = 0; j < 4; ++j) {
      int r = vsr + j * 16;
      *(int4*)&Vs[r * 132 + vsc] = *(const int4*)(vg + (size_t)r * S + t0 + vsc);
    }
    __syncthreads();
    if (t0 + 128 <= q0)
      attn_tile<8, false>(t0, qcol, qa0, qa1, Ks, Vs, Psw, o, lsum, lrow, lgrp);
    else if (tend - t0 >= 128)
      attn_tile<8, true>(t0, qcol, qa0, qa1, Ks, Vs, Psw, o, lsum, lrow, lgrp);
    else
      attn_tile<4, true>(t0, qcol, qa0, qa1, Ks, Vs, Psw, o, lsum, lrow, lgrp);
    __syncthreads();
  }

  // l lives per-lane for q = lrow; reduce across lgrp, then redistribute to
  // the O C-layout rows (q = lgrp*4 + r).
  lsum += __shfl_xor(lsum, 16, 64);
  lsum += __shfl_xor(lsum, 32, 64);
  float inv[4];
#pragma unroll
  for (int r = 0; r < 4; ++r)
    inv[r] = 1.0f / __shfl(lsum, lgrp * 20 + r, 64);  // srcLane: lrow = lgrp*4+r
  unsigned short* op = ctx + (size_t)(b * S + q0w) * D + h * 64;
#pragma unroll
  for (int nb = 0; nb < 4; ++nb)
#pragma unroll
    for (int r = 0; r < 4; ++r) {
      int row = lgrp * 4 + r;
      op[(size_t)row * D + nb * 16 + lrow] = f2bf(o[nb][r] * inv[r]);
    }
}

// ---------------------------------- launch ----------------------------------
extern "C" void kernel_launch(void* const* d_in, const int* in_sizes, int n_in,
                              void* d_out, int out_size, void* d_ws, size_t ws_size,
                              hipStream_t stream) {
  const float* x       = (const float*)d_in[0];   // [2,2048,1024] fp32
  const float* W_qkv   = (const float*)d_in[1];   // [1024,3072] fp32
  const float* q_scale = (const float*)d_in[2];   // [1024] fp32
  const float* k_scale = (const float*)d_in[3];   // [1024] fp32
  const float* W_out   = (const float*)d_in[4];   // [1024,1024] fp32
  float* out = (float*)d_out;                     // [2,2048,1024] fp32
  char* ws = (char*)d_ws;
  unsigned short* WT_qkv = (unsigned short*)(ws + 0);         //  6291456
  unsigned short* WT_out = (unsigned short*)(ws + 6291456);   //  2097152
  unsigned short* qkv    = (unsigned short*)(ws + 8388608);   // 25165824
  unsigned short* q_nb   = (unsigned short*)(ws + 33554432);  //  8388608
  unsigned short* k_nb   = (unsigned short*)(ws + 41943040);  //  8388608
  unsigned short* VT     = (unsigned short*)(ws + 50331648);  //  8388608
  unsigned short* x_bf   = (unsigned short*)(ws + 58720256);  //  8388608 -> 64 MiB
  unsigned short* ctx    = qkv;  // alias: qkv dead after k_lnv

  k_prep<<<8192, 256, 0, stream>>>(x, W_qkv, W_out, x_bf, WT_qkv, WT_out);
  k_gemm_bt<128, false><<<dim3(32, 24), 256, 0, stream>>>(x_bf, WT_qkv, qkv, 4096, 3072, 1024);
  k_lnv<<<8192, 256, 0, stream>>>(qkv, q_scale, k_scale, q_nb, k_nb, VT);
  k_flash<<<dim3(32, 32), 256, 0, stream>>>(q_nb, k_nb, VT, ctx);
  k_gemm_bt<64, true><<<dim3(64, 8), 256, 0, stream>>>(ctx, WT_out, out, 4096, 1024, 1024);
}

// Round 7
// 189.009 us; speedup vs baseline: 1.3429x; 1.3429x over previous
//
#include <hip/hip_runtime.h>
#include <cstdint>
#include <cstddef>

typedef __attribute__((ext_vector_type(8))) short short8;   // 8 bf16 = 4 VGPRs (MFMA A/B frag)
typedef __attribute__((ext_vector_type(4))) float floatx4;  // MFMA C/D frag

__device__ __forceinline__ float bf2f(unsigned short u) {
  union { unsigned int i; float f; } c; c.i = ((unsigned int)u) << 16; return c.f;
}
__device__ __forceinline__ unsigned short f2bf(float f) {
  union { float f; unsigned int i; } c; c.f = f;
  unsigned int r = c.i + 0x7fffu + ((c.i >> 16) & 1u);  // round-nearest-even
  return (unsigned short)(r >> 16);
}
__device__ __forceinline__ unsigned int fbits(float f) {
  union { float f; unsigned int i; } c; c.f = f; return c.i;
}

// async global->LDS, 16 B per lane; LDS dest = wave-uniform base + lane*16 (m97/m104)
__device__ __forceinline__ void glds16(const unsigned short* g, unsigned short* l) {
  __builtin_amdgcn_global_load_lds((const __attribute__((address_space(1))) void*)g,
                                   (__attribute__((address_space(3))) void*)l, 16, 0, 0);
}

// ---- 32x32 transpose+cvt tile helper (256 threads, 4 rows/thread) ----
__device__ __forceinline__ void tr_tile(const float* __restrict__ in,
                                        unsigned short* __restrict__ out,
                                        int R, int C, int bx, int by, int tid,
                                        unsigned short (*t)[33]) {
  const int cx = tid & 31, rl = tid >> 5;
#pragma unroll
  for (int i = 0; i < 4; ++i)
    t[rl + i * 8][cx] = f2bf(in[(size_t)(by * 32 + rl + i * 8) * C + bx * 32 + cx]);
  __syncthreads();
  const int oc = by * 32 + cx;
#pragma unroll
  for (int i = 0; i < 4; ++i)
    out[(size_t)(bx * 32 + rl + i * 8) * R + oc] = t[cx][rl + i * 8];
}

// ---- fused prep: W_qkv^T (3072 blks) + W_out^T (1024 blks) + x cvt (4096 blks) ----
__global__ __launch_bounds__(256) void k_prep(const float* __restrict__ x,
                                              const float* __restrict__ Wq,
                                              const float* __restrict__ Wo,
                                              unsigned short* __restrict__ x_bf,
                                              unsigned short* __restrict__ WTq,
                                              unsigned short* __restrict__ WTo) {
  __shared__ unsigned short t[32][33];
  const int bid = blockIdx.x, tid = threadIdx.x;
  if (bid < 3072) {
    tr_tile(Wq, WTq, 1024, 3072, bid % 96, bid / 96, tid, t);
  } else if (bid < 4096) {
    int v = bid - 3072;
    tr_tile(Wo, WTo, 1024, 1024, v & 31, v >> 5, tid, t);
  } else {
    int i = (bid - 4096) * 256 + tid;
    float4 v = ((const float4*)x)[i];
    ushort4 o = { f2bf(v.x), f2bf(v.y), f2bf(v.z), f2bf(v.w) };
    ((ushort4*)x_bf)[i] = o;
  }
}

// ---------------- GEMM: C[M][N] = A[M][K] * BT[N][K]^T, bf16 in ----------------
// m97 structure, MT x 128 tile, BK=32, global_load_lds width-16 staging.
template <int MT, bool F32OUT>
__global__ __launch_bounds__(256) void k_gemm_bt(const unsigned short* __restrict__ A,
                                                 const unsigned short* __restrict__ BT,
                                                 void* __restrict__ Cout,
                                                 int M, int N, int K) {
  constexpr int NI = MT / 32;  // per-wave m-frag count (4 or 2)
  __shared__ unsigned short As[MT * 32];
  __shared__ unsigned short Bs[128 * 32];
  const int bm = blockIdx.x * MT, bn = blockIdx.y * 128;
  const int tid = threadIdx.x;
  const int wave = tid >> 6, lane = tid & 63;
  const int wm = (wave & 1) * (MT / 2), wn = (wave >> 1) * 64;
  const int lrow = lane & 15, lgrp = lane >> 4;
  floatx4 acc[NI][4] = {};

  const int lr4 = lane >> 2, lc8 = (lane & 3) * 8;
  const int br0 = wave * 32;
  const unsigned short* Bg0 = BT + (size_t)(bn + br0 + lr4) * K + lc8;
  const unsigned short* Bg1 = BT + (size_t)(bn + br0 + 16 + lr4) * K + lc8;
  unsigned short* lB0 = &Bs[br0 * 32];
  unsigned short* lB1 = &Bs[(br0 + 16) * 32];
  const int ar0 = wave * (MT / 4);
  const unsigned short* Ag0 = A + (size_t)(bm + ar0 + lr4) * K + lc8;
  const unsigned short* Ag1 = A + (size_t)(bm + ar0 + 16 + lr4) * K + lc8;  // MT==128 only
  unsigned short* lA0 = &As[ar0 * 32];
  unsigned short* lA1 = &As[(ar0 + 16) * 32];

  for (int k0 = 0; k0 < K; k0 += 32) {
    glds16(Ag0 + k0, lA0);
    if (MT == 128) glds16(Ag1 + k0, lA1);
    glds16(Bg0 + k0, lB0);
    glds16(Bg1 + k0, lB1);
    __syncthreads();
    short8 a[NI], bfr[4];
#pragma unroll
    for (int i = 0; i < NI; ++i)
      a[i] = *(const short8*)&As[(wm + i * 16 + lrow) * 32 + lgrp * 8];
#pragma unroll
    for (int j = 0; j < 4; ++j)
      bfr[j] = *(const short8*)&Bs[(wn + j * 16 + lrow) * 32 + lgrp * 8];
#pragma unroll
    for (int i = 0; i < NI; ++i)
#pragma unroll
      for (int j = 0; j < 4; ++j)
        acc[i][j] = __builtin_amdgcn_mfma_f32_16x16x32_bf16(a[i], bfr[j], acc[i][j], 0, 0, 0);
    __syncthreads();
  }
#pragma unroll
  for (int i = 0; i < NI; ++i)
#pragma unroll
    for (int j = 0; j < 4; ++j)
#pragma unroll
      for (int r = 0; r < 4; ++r) {
        int m = bm + wm + i * 16 + lgrp * 4 + r;
        int n = bn + wn + j * 16 + lrow;
        if (F32OUT)
          ((float*)Cout)[(size_t)m * N + n] = acc[i][j][r];
        else
          ((unsigned short*)Cout)[(size_t)m * N + n] = f2bf(acc[i][j][r]);
      }
}

// ---- fused LN (4096 blks) + V transpose (4096 blks); both read qkv ----
// LN: q out folded by 0.125*log2(e) so flash uses exp2 directly.
__global__ __launch_bounds__(256) void k_lnv(const unsigned short* __restrict__ qkv,
                                             const float* __restrict__ q_scale,
                                             const float* __restrict__ k_scale,
                                             unsigned short* __restrict__ q_n,
                                             unsigned short* __restrict__ k_n,
                                             unsigned short* __restrict__ VT) {
  const int bid = blockIdx.x, tid = threadIdx.x;
  if (bid < 4096) {
    const int tok = bid;
    const int wave = tid >> 6, lane = tid & 63;
    __shared__ float red[2][4];
    const unsigned short* row = qkv + (size_t)tok * 3072;
#pragma unroll
    for (int seg = 0; seg < 2; ++seg) {
      const unsigned short* p  = row + seg * 1024;
      const float* sc = seg ? k_scale : q_scale;
      unsigned short* outp = (seg ? k_n : q_n) + (size_t)tok * 1024;
      ushort4 u = *(const ushort4*)&p[tid * 4];
      float xv[4] = { bf2f(u.x), bf2f(u.y), bf2f(u.z), bf2f(u.w) };
      float sum = xv[0] + xv[1] + xv[2] + xv[3];
      float sq  = xv[0]*xv[0] + xv[1]*xv[1] + xv[2]*xv[2] + xv[3]*xv[3];
      for (int off = 32; off; off >>= 1) {
        sum += __shfl_down(sum, off, 64);
        sq  += __shfl_down(sq,  off, 64);
      }
      if (lane == 0) { red[0][wave] = sum; red[1][wave] = sq; }
      __syncthreads();
      sum = red[0][0] + red[0][1] + red[0][2] + red[0][3];
      sq  = red[1][0] + red[1][1] + red[1][2] + red[1][3];
      __syncthreads();
      float mean = sum * (1.0f / 1024.0f);
      float var  = sq * (1.0f / 1024.0f) - mean * mean;
      float rstd = rsqrtf(var + 1e-6f);
      if (seg == 0) rstd *= 0.18033688011112042f;  // 0.125 * log2(e)
      float4 su = *(const float4*)&sc[tid * 4];
      ushort4 o;
      o.x = f2bf((xv[0] - mean) * rstd * su.x);
      o.y = f2bf((xv[1] - mean) * rstd * su.y);
      o.z = f2bf((xv[2] - mean) * rstd * su.z);
      o.w = f2bf((xv[3] - mean) * rstd * su.w);
      *(ushort4*)&outp[tid * 4] = o;
    }
  } else {
    // V transpose tile: v-part [b,s,h*64+hd] -> VT[(b*16+h)*64+hd][s]
    __shared__ unsigned short t[32][33];
    const int v = bid - 4096;
    const int bh = v & 31, b = bh >> 4, h = bh & 15;
    const int sy = (v >> 5) & 63, hx = v >> 11;   // s-tile 0..63, hd-tile 0..1
    const int cx = tid & 31, rl = tid >> 5;
#pragma unroll
    for (int i = 0; i < 4; ++i)
      t[rl + i * 8][cx] =
        qkv[(size_t)(b * 2048 + sy * 32 + rl + i * 8) * 3072 + 2048 + h * 64 + hx * 32 + cx];
    __syncthreads();
#pragma unroll
    for (int i = 0; i < 4; ++i)
      VT[((size_t)bh * 64 + hx * 32 + rl + i * 8) * 2048 + sy * 32 + cx] = t[cx][rl + i * 8];
  }
}

// ------------------------------ flash attention ------------------------------
// Fixed-max softmax (m=0, validated r4/r5). S^T = K Q^T (lane: t=lgrp*4+r,
// q=lrow). P stored TRUNCATED via high-half packing; l exact in fp32.
// STRIDES: 72 / 136 / 136 — 136*2 = 272 B = 17*16 B keeps every b128 LDS
// access 16-B aligned (r6's 132 broke alignment -> 2.3x regression).
template <int TB, bool MASKED>
__device__ __forceinline__ void attn_tile(int t0, int qcol,
    const short8 qa0, const short8 qa1,
    const unsigned short* Ks, const unsigned short* Vs, unsigned short* Psw,
    floatx4 (&o)[4], float& lsum, int lrow, int lgrp) {
#pragma unroll
  for (int tb = 0; tb < TB; ++tb) {
    floatx4 st = {};
    short8 kb0 = *(const short8*)&Ks[(tb * 16 + lrow) * 72 + lgrp * 8];
    st = __builtin_amdgcn_mfma_f32_16x16x32_bf16(kb0, qa0, st, 0, 0, 0);
    short8 kb1 = *(const short8*)&Ks[(tb * 16 + lrow) * 72 + 32 + lgrp * 8];
    st = __builtin_amdgcn_mfma_f32_16x16x32_bf16(kb1, qa1, st, 0, 0, 0);
    float p0 = exp2f(st[0]), p1 = exp2f(st[1]);
    float p2 = exp2f(st[2]), p3 = exp2f(st[3]);
    if (MASKED) {
      const int tbase = t0 + tb * 16 + lgrp * 4;
      p0 = (tbase     <= qcol) ? p0 : 0.0f;
      p1 = (tbase + 1 <= qcol) ? p1 : 0.0f;
      p2 = (tbase + 2 <= qcol) ? p2 : 0.0f;
      p3 = (tbase + 3 <= qcol) ? p3 : 0.0f;
    }
    lsum += (p0 + p1) + (p2 + p3);
    uint2 pu;
    pu.x = (fbits(p0) >> 16) | (fbits(p1) & 0xFFFF0000u);  // trunc-pack
    pu.y = (fbits(p2) >> 16) | (fbits(p3) & 0xFFFF0000u);
    *(uint2*)&Psw[lrow * 136 + tb * 16 + lgrp * 4] = pu;
  }
#pragma unroll
  for (int kk = 0; kk < TB / 2; ++kk) {
    short8 pa = *(const short8*)&Psw[lrow * 136 + kk * 32 + lgrp * 8];
#pragma unroll
    for (int nb = 0; nb < 4; ++nb) {
      short8 vb = *(const short8*)&Vs[(nb * 16 + lrow) * 136 + kk * 32 + lgrp * 8];
      o[nb] = __builtin_amdgcn_mfma_f32_16x16x32_bf16(pa, vb, o[nb], 0, 0, 0);
    }
  }
}

// grid (32 bh, 32 qt): linear id % 8 = bh % 8 -> one bh per XCD (L2 locality).
// qt reversed: heavy diagonal blocks first. block 256 = 4 waves x 16 Q-rows.
// LDS 53248 B; 3 blocks/CU (3*53248 = 159744 <= 163840).
__global__ __launch_bounds__(256) void k_flash(const unsigned short* __restrict__ q_n,
                                               const unsigned short* __restrict__ k_n,
                                               const unsigned short* __restrict__ VT,
                                               unsigned short* __restrict__ ctx) {
  const int S = 2048, D = 1024;
  const int bh = blockIdx.x, b = bh >> 4, h = bh & 15;
  const int qt = 31 - (int)blockIdx.y;
  const int q0 = qt * 64;
  const int tid = threadIdx.x, wave = tid >> 6, lane = tid & 63;
  const int lrow = lane & 15, lgrp = lane >> 4;
  __shared__ unsigned short Ks[128 * 72];     // [t][hd]
  __shared__ unsigned short Vs[64 * 136];     // [hd][t]
  __shared__ unsigned short Ps[4][16 * 136];  // per-wave P [q][t]
  unsigned short* Psw = Ps[wave];

  const unsigned short* kg = k_n + (size_t)(b * S) * D + h * 64;
  const unsigned short* vg = VT + (size_t)bh * 64 * S;
  const int ksr = tid >> 3, ksc = (tid & 7) * 8;    // K staging: 32 rows/pass
  const int vsr = tid >> 4, vsc = (tid & 15) * 8;   // V staging: 16 rows/pass

  const int q0w = q0 + wave * 16;
  const int qcol = q0w + lrow;                       // this lane's q row (S^T col)
  const unsigned short* qp = q_n + (size_t)(b * S + qcol) * D + h * 64;
  const short8 qa0 = *(const short8*)(qp + lgrp * 8);
  const short8 qa1 = *(const short8*)(qp + 32 + lgrp * 8);
  floatx4 o[4] = {};
  float lsum = 0.0f;

  const int tend = q0 + 64;
  for (int t0 = 0; t0 < tend; t0 += 128) {
#pragma unroll
    for (int j = 0; j < 4; ++j) {
      int r = ksr + j * 32;
      *(int4*)&Ks[r * 72 + ksc] = *(const int4*)(kg + (size_t)(t0 + r) * D + ksc);
    }
#pragma unroll
    for (int j = 0; j < 4; ++j) {
      int r = vsr + j * 16;
      *(int4*)&Vs[r * 136 + vsc] = *(const int4*)(vg + (size_t)r * S + t0 + vsc);
    }
    __syncthreads();
    if (t0 + 128 <= q0)
      attn_tile<8, false>(t0, qcol, qa0, qa1, Ks, Vs, Psw, o, lsum, lrow, lgrp);
    else if (tend - t0 >= 128)
      attn_tile<8, true>(t0, qcol, qa0, qa1, Ks, Vs, Psw, o, lsum, lrow, lgrp);
    else
      attn_tile<4, true>(t0, qcol, qa0, qa1, Ks, Vs, Psw, o, lsum, lrow, lgrp);
    __syncthreads();
  }

  // l lives per-lane for q = lrow; reduce across lgrp, then redistribute to
  // the O C-layout rows (q = lgrp*4 + r).
  lsum += __shfl_xor(lsum, 16, 64);
  lsum += __shfl_xor(lsum, 32, 64);
  float inv[4];
#pragma unroll
  for (int r = 0; r < 4; ++r)
    inv[r] = 1.0f / __shfl(lsum, lgrp * 20 + r, 64);  // srcLane: lrow = lgrp*4+r
  unsigned short* op = ctx + (size_t)(b * S + q0w) * D + h * 64;
#pragma unroll
  for (int nb = 0; nb < 4; ++nb)
#pragma unroll
    for (int r = 0; r < 4; ++r) {
      int row = lgrp * 4 + r;
      op[(size_t)row * D + nb * 16 + lrow] = f2bf(o[nb][r] * inv[r]);
    }
}

// ---------------------------------- launch ----------------------------------
extern "C" void kernel_launch(void* const* d_in, const int* in_sizes, int n_in,
                              void* d_out, int out_size, void* d_ws, size_t ws_size,
                              hipStream_t stream) {
  const float* x       = (const float*)d_in[0];   // [2,2048,1024] fp32
  const float* W_qkv   = (const float*)d_in[1];   // [1024,3072] fp32
  const float* q_scale = (const float*)d_in[2];   // [1024] fp32
  const float* k_scale = (const float*)d_in[3];   // [1024] fp32
  const float* W_out   = (const float*)d_in[4];   // [1024,1024] fp32
  float* out = (float*)d_out;                     // [2,2048,1024] fp32
  char* ws = (char*)d_ws;
  unsigned short* WT_qkv = (unsigned short*)(ws + 0);         //  6291456
  unsigned short* WT_out = (unsigned short*)(ws + 6291456);   //  2097152
  unsigned short* qkv    = (unsigned short*)(ws + 8388608);   // 25165824
  unsigned short* q_nb   = (unsigned short*)(ws + 33554432);  //  8388608
  unsigned short* k_nb   = (unsigned short*)(ws + 41943040);  //  8388608
  unsigned short* VT     = (unsigned short*)(ws + 50331648);  //  8388608
  unsigned short* x_bf   = (unsigned short*)(ws + 58720256);  //  8388608 -> 64 MiB
  unsigned short* ctx    = qkv;  // alias: qkv dead after k_lnv

  k_prep<<<8192, 256, 0, stream>>>(x, W_qkv, W_out, x_bf, WT_qkv, WT_out);
  k_gemm_bt<128, false><<<dim3(32, 24), 256, 0, stream>>>(x_bf, WT_qkv, qkv, 4096, 3072, 1024);
  k_lnv<<<8192, 256, 0, stream>>>(qkv, q_scale, k_scale, q_nb, k_nb, VT);
  k_flash<<<dim3(32, 32), 256, 0, stream>>>(q_nb, k_nb, VT, ctx);
  k_gemm_bt<64, true><<<dim3(64, 8), 256, 0, stream>>>(ctx, WT_out, out, 4096, 1024, 1024);
}